// Round 14
// baseline (44.881 us; speedup 1.0000x reference)
//
#include <hip/hip_runtime.h>
#include <math.h>

#define NP 16384   // spatial positions = 32*32*16
#define HDIM 32
#define WDIM 32
#define ZDIM 16

typedef short bf16x8 __attribute__((ext_vector_type(8)));
typedef unsigned short u16x8 __attribute__((ext_vector_type(8)));
typedef unsigned short u16x4 __attribute__((ext_vector_type(4)));
typedef float f32x4 __attribute__((ext_vector_type(4)));

__device__ __forceinline__ unsigned short f2bf(float f) {
    unsigned int u = __float_as_uint(f);
    return (unsigned short)((u + 0x7fffu + ((u >> 16) & 1u)) >> 16);
}

// pack 8 consecutive f32 -> bf16x8 (two float4 loads)
__device__ __forceinline__ bf16x8 cvt8(const float* __restrict__ p) {
    const float4 w0 = *(const float4*)p;
    const float4 w1 = *(const float4*)(p + 4);
    bf16x8 v;
    v[0] = (short)f2bf(w0.x); v[1] = (short)f2bf(w0.y);
    v[2] = (short)f2bf(w0.z); v[3] = (short)f2bf(w0.w);
    v[4] = (short)f2bf(w1.x); v[5] = (short)f2bf(w1.y);
    v[6] = (short)f2bf(w1.z); v[7] = (short)f2bf(w1.w);
    return v;
}

#define PROW 320               // 160 keys * 2 B per q-row
#define PWAVE (16 * PROW)      // 5120 B per wave

// ---------------------------------------------------------------------------
// Single fused kernel: per-block redundant-halo QKV + attention + projection.
// Block (bx, h) owns 32 positions (w-cols 2bx,2bx+1, all z of row h) and
// stages/computes QKV for the 3x4x16 = 192-position halo entirely in LDS.
//   phase 0: stage x[192 pos][128 ch] f32 -> bf16 swizzled LDS (T14 split:
//            loads issued before the weight cvt that hides them)
//   phase 1: QKV GEMM (8 waves x 144 MFMA): Q(own 32)->Qs, K->Ks, V->VTs
//   phase 2: attention (identical math to 2-kernel version, LDS sources)
//   phase 3: projection Wp . As + bp -> out
// LDS: XPA 48K (Xs, later P 40K + As 8K) + Ks 48K + VTs 48K + Qs 8K + 2K rpb
//    = 154 KB -> 1 block/CU.  Grid (16, 32), 512 threads.
// ---------------------------------------------------------------------------
__global__ __launch_bounds__(512) void natten_mega(
    const float* __restrict__ x, const float* __restrict__ Wqkv,
    const float* __restrict__ bqkv, const float* __restrict__ rpb,
    const float* __restrict__ Wp, const float* __restrict__ bp,
    float* __restrict__ out)
{
    __shared__ __align__(16) unsigned char XPA[49152];  // Xs; later P+As
    __shared__ __align__(16) unsigned char Ks[49152];   // [192][128ch] bf16 swz
    __shared__ __align__(16) unsigned char VTs[49152];  // [128ch][192] bf16 swz
    __shared__ __align__(16) unsigned char Qs[8192];    // [32][128ch] bf16 swz
    __shared__ float bias_s[500];

    const int tid  = threadIdx.x;
    const int bx   = blockIdx.x;
    const int h    = blockIdx.y;
    const int lane = tid & 63;
    const int wv   = tid >> 6;
    const int l15  = lane & 15;
    const int kg   = lane >> 4;

    const int hs     = min(max(h - 1, 0), HDIM - 3);
    const int wstart = min(max(2 * bx - 1, 0), WDIM - 4);
    const int dh_own = h - hs;                 // local h-row of own positions
    const int dwc0   = 2 * bx - wstart;        // local w-col of own w0

    if (tid < 500) bias_s[tid] = rpb[tid];

    // ---- phase 0a (T14 issue): x loads into registers. item = dh|cg|pr,
    // pr = dwc*16+z runs over 64 contiguous positions per h-row -> coalesced.
    float xv[6][8];
    #pragma unroll
    for (int it = 0; it < 6; ++it) {
        const int item = tid + it * 512;       // 0..3071
        const int pr = item & 63;
        const int cg = (item >> 6) & 15;
        const int dh = item >> 10;             // 0..2
        const int gpos = (hs + dh) * 512 + wstart * 16 + pr;
        #pragma unroll
        for (int j = 0; j < 8; ++j)
            xv[it][j] = x[(cg * 8 + j) * NP + gpos];
    }

    // ---- weight fragments (independent; latency hides under x loads)
    const int wrow = wv * 48;                  // GEMM rows of this wave
    bf16x8 a[3][4];
    float  b4[3][4];
    #pragma unroll
    for (int t = 0; t < 3; ++t) {
        const int row = wrow + t * 16 + l15;
        #pragma unroll
        for (int kb = 0; kb < 4; ++kb)
            a[t][kb] = cvt8(&Wqkv[row * 128 + kb * 32 + kg * 8]);
        #pragma unroll
        for (int r = 0; r < 4; ++r)
            b4[t][r] = bqkv[wrow + t * 16 + kg * 4 + r];
    }
    const int prow0 = wv * 16;                 // projection rows of this wave
    bf16x8 aw[4];
    {
        const int ab = (prow0 + l15) * 128 + kg * 8;
        #pragma unroll
        for (int kb = 0; kb < 4; ++kb)
            aw[kb] = cvt8(&Wp[ab + kb * 32]);
    }
    float bpr[4];
    #pragma unroll
    for (int r = 0; r < 4; ++r) bpr[r] = bp[prow0 + kg * 4 + r];

    // ---- phase 0b (T14 write): convert x, store to swizzled Xs
    #pragma unroll
    for (int it = 0; it < 6; ++it) {
        const int item = tid + it * 512;
        const int pr = item & 63;
        const int cg = (item >> 6) & 15;
        const int dh = item >> 10;
        const int lp = dh * 64 + pr;
        u16x8 v8;
        #pragma unroll
        for (int j = 0; j < 8; ++j) v8[j] = f2bf(xv[it][j]);
        *(u16x8*)(XPA + lp * 256 + ((cg * 16) ^ ((lp & 7) << 4))) = v8;
    }
    __syncthreads();

    // ---- phase 1: QKV GEMM, 12 col-tiles x 3 row-tiles x 4 K-blocks
    #pragma unroll
    for (int ct = 0; ct < 12; ++ct) {
        const int lp = ct * 16 + l15;
        bf16x8 bfr[4];
        #pragma unroll
        for (int kb = 0; kb < 4; ++kb)
            bfr[kb] = *(const bf16x8*)(XPA + lp * 256 +
                                       ((kb * 64 + kg * 16) ^ ((lp & 7) << 4)));
        #pragma unroll
        for (int t = 0; t < 3; ++t) {
            f32x4 acc = {0.f, 0.f, 0.f, 0.f};
            __builtin_amdgcn_s_setprio(1);
            #pragma unroll
            for (int kb = 0; kb < 4; ++kb)
                acc = __builtin_amdgcn_mfma_f32_16x16x32_bf16(a[t][kb], bfr[kb], acc, 0, 0, 0);
            __builtin_amdgcn_s_setprio(0);
            const int r0 = wrow + t * 16;
            if (r0 < 128) {
                // Q: only own columns (wave-uniform condition)
                const int dh  = ct >> 2;
                const int dwc = ct & 3;
                const int dd  = dwc - dwc0;
                if (dh == dh_own && (unsigned)dd < 2u) {
                    const int po = dd * 16 + l15;
                    u16x4 ph;
                    #pragma unroll
                    for (int r = 0; r < 4; ++r)
                        ph[r] = f2bf((acc[r] + b4[t][r]) * 0.17677669529663687f);
                    *(u16x4*)(Qs + po * 256 +
                              (((r0 + kg * 4) * 2) ^ ((po & 7) << 4))) = ph;
                }
            } else if (r0 < 256) {
                u16x4 ph;
                #pragma unroll
                for (int r = 0; r < 4; ++r) ph[r] = f2bf(acc[r] + b4[t][r]);
                *(u16x4*)(Ks + lp * 256 +
                          (((r0 - 128 + kg * 4) * 2) ^ ((lp & 7) << 4))) = ph;
            } else {
                #pragma unroll
                for (int r = 0; r < 4; ++r) {
                    const int ch = r0 - 256 + kg * 4 + r;
                    *(unsigned short*)(VTs + ch * 384 +
                                       ((lp * 2) ^ ((ch & 7) << 4))) =
                        f2bf(acc[r] + b4[t][r]);
                }
            }
        }
    }
    __syncthreads();

    // ---- phase 2: attention.  wave -> (head, wcol)
    const int head = wv >> 1;
    const int wcol = wv & 1;
    const int w    = 2 * bx + wcol;
    const int ws_  = min(max(w - 1, 0), WDIM - 3);
    const int ow   = ws_ - wstart;             // local col of this wave's window
    const int rh0  = 2 - dh_own;
    const int rw0  = ws_ - w + 2;
    const int cb   = head * 32;
    const int z    = l15;
    const int zs   = min(max(z - 1, 0), ZDIM - 3);

    int   idxc[4];
    float vmask[4];
    #pragma unroll
    for (int r = 0; r < 4; ++r) {
        const int zp = kg * 4 + r;
        const int dz = zp - z + 2;
        idxc[r]  = min(max(dz, 0), 4);
        vmask[r] = (zp >= zs && zp <= zs + 2) ? 1.f : 0.f;
    }
    float biasv[9][4];
    #pragma unroll
    for (int g = 0; g < 9; ++g) {
        const int bbase = head * 125 + ((rh0 + g / 3) * 5 + (rw0 + g % 3)) * 5;
        #pragma unroll
        for (int r = 0; r < 4; ++r)
            biasv[g][r] = bias_s[bbase + idxc[r]];
    }

    const int qrow = wcol * 16 + l15;
    const bf16x8 bq = *(const bf16x8*)(Qs + qrow * 256 +
                                       ((cb * 2 + kg * 16) ^ ((qrow & 7) << 4)));

    float sv[9][4];
    float m = -1e30f;
    __builtin_amdgcn_s_setprio(1);
    #pragma unroll
    for (int g = 0; g < 9; ++g) {
        const int gl = (g / 3) * 4 + ow + g % 3;   // local column group
        const bf16x8 ak = *(const bf16x8*)(Ks + (gl * 16 + l15) * 256 +
                                           ((cb * 2 + kg * 16) ^ ((l15 & 7) << 4)));
        f32x4 st = {0.f, 0.f, 0.f, 0.f};
        st = __builtin_amdgcn_mfma_f32_16x16x32_bf16(ak, bq, st, 0, 0, 0);
        #pragma unroll
        for (int r = 0; r < 4; ++r) {
            sv[g][r] = st[r] + biasv[g][r];
            m = fmaxf(m, sv[g][r]);
        }
    }
    __builtin_amdgcn_s_setprio(0);
    m = fmaxf(m, __shfl_xor(m, 16, 64));
    m = fmaxf(m, __shfl_xor(m, 32, 64));

    float sum = 0.f;
    #pragma unroll
    for (int g = 0; g < 9; ++g)
        #pragma unroll
        for (int r = 0; r < 4; ++r) {
            sv[g][r] = __expf(sv[g][r] - m) * vmask[r];
            sum += sv[g][r];
        }
    sum += __shfl_xor(sum, 16, 64);
    sum += __shfl_xor(sum, 32, 64);
    const float inv = 1.f / sum;

    unsigned char* Pw = XPA + wv * PWAVE;      // aliases Xs (dead after GEMM)
    #pragma unroll
    for (int g = 0; g < 9; ++g) {
        u16x4 pk;
        #pragma unroll
        for (int r = 0; r < 4; ++r) pk[r] = f2bf(sv[g][r]);
        const int off = (z * PROW + (16 * g + kg * 4) * 2) ^ ((z & 7) << 4);
        *(u16x4*)(Pw + off) = pk;
    }
    {   // zero-pad keys 144..159
        u16x4 zq = {0, 0, 0, 0};
        const int off = (z * PROW + (144 + kg * 4) * 2) ^ ((z & 7) << 4);
        *(u16x4*)(Pw + off) = zq;
    }

    float invr[4];
    #pragma unroll
    for (int r = 0; r < 4; ++r)
        invr[r] = __shfl(inv, (lane & 48) | (kg * 4 + r), 64);

    unsigned char* As = XPA + 40960;           // 8 KB attn tile after P region

    #pragma unroll
    for (int ct = 0; ct < 2; ++ct) {
        f32x4 acc = {0.f, 0.f, 0.f, 0.f};
        __builtin_amdgcn_s_setprio(1);
        #pragma unroll
        for (int kb = 0; kb < 5; ++kb) {
            const int off = (z * PROW + (kb * 32 + kg * 8) * 2) ^ ((z & 7) << 4);
            const bf16x8 ap = *(const bf16x8*)(Pw + off);
            const int ga = 2 * kb;
            const int gb = (2 * kb + 1 > 8) ? 8 : 2 * kb + 1;
            const int gx = (kg & 2) ? gb : ga;
            const int glv = (gx / 3) * 4 + ow + gx % 3;
            const int zoff = (kg & 1) * 8;
            const int ch = cb + ct * 16 + l15;
            const bf16x8 bv = *(const bf16x8*)(VTs + ch * 384 +
                                  (((glv * 16 + zoff) * 2) ^ ((ch & 7) << 4)));
            acc = __builtin_amdgcn_mfma_f32_16x16x32_bf16(ap, bv, acc, 0, 0, 0);
        }
        __builtin_amdgcn_s_setprio(0);
        #pragma unroll
        for (int r = 0; r < 4; ++r) {
            const int pl = wcol * 16 + kg * 4 + r;       // local position 0..31
            const int ch = cb + ct * 16 + l15;           // channel 0..127
            const int byte = pl * 256 + ((ch * 2) ^ ((pl & 7) << 4));
            *(unsigned short*)(As + byte) = f2bf(acc[r] * invr[r]);
        }
    }

    __syncthreads();

    // ---- phase 3: projection.  Wave wv -> out rows prow0..+15, 32 positions.
    const int pcol0 = (h * 32 + 2 * bx) * 16;

    #pragma unroll
    for (int ct = 0; ct < 2; ++ct) {
        const int pl = ct * 16 + l15;
        f32x4 acc = {0.f, 0.f, 0.f, 0.f};
        #pragma unroll
        for (int kb = 0; kb < 4; ++kb) {
            const int byte = pl * 256 + ((kb * 64 + kg * 16) ^ ((pl & 7) << 4));
            const bf16x8 bh = *(const bf16x8*)(As + byte);
            acc = __builtin_amdgcn_mfma_f32_16x16x32_bf16(aw[kb], bh, acc, 0, 0, 0);
        }
        #pragma unroll
        for (int r = 0; r < 4; ++r)
            out[(prow0 + kg * 4 + r) * NP + pcol0 + ct * 16 + l15] = acc[r] + bpr[r];
    }
}

// ---------------------------------------------------------------------------
extern "C" void kernel_launch(void* const* d_in, const int* in_sizes, int n_in,
                              void* d_out, int out_size, void* d_ws, size_t ws_size,
                              hipStream_t stream)
{
    const float* x    = (const float*)d_in[0];
    const float* Wqkv = (const float*)d_in[1];
    const float* bqkv = (const float*)d_in[2];
    const float* rpb  = (const float*)d_in[3];
    const float* Wp   = (const float*)d_in[4];
    const float* bp   = (const float*)d_in[5];
    float* out = (float*)d_out;

    natten_mega<<<dim3(16, 32), dim3(512), 0, stream>>>(
        x, Wqkv, bqkv, rpb, Wp, bp, out);
}